// Round 4
// baseline (218.012 us; speedup 1.0000x reference)
//
#include <hip/hip_runtime.h>
#include <hip/hip_bf16.h>
#include <math.h>

#define N 1024
#define F 128
#define NEG_SLOPE 0.01f

typedef float f32x4 __attribute__((ext_vector_type(4)));

// Kernel 1: Vp = V @ W^T + b ; s_i = Vp @ a_i ; s_j = Vp @ a_j
__global__ __launch_bounds__(128) void gat_prep(
    const float* __restrict__ V,     // N*F
    const float* __restrict__ W,     // F*F
    const float* __restrict__ b,     // F
    const float* __restrict__ a,     // 3F: [a_i | a_j | a_t]
    float* __restrict__ Vp,          // N*F
    float* __restrict__ s_i,         // N
    float* __restrict__ s_j)         // N
{
    const int i = blockIdx.x;
    const int f = threadIdx.x;        // 0..127
    __shared__ float vsh[F];
    vsh[f] = V[i * F + f];
    __syncthreads();

    const float* wrow = W + f * F;
    float acc = b[f];
#pragma unroll 4
    for (int k = 0; k < F; ++k) acc += vsh[k] * wrow[k];
    Vp[(size_t)i * F + f] = acc;

    float pi = acc * a[f];
    float pj = acc * a[F + f];
#pragma unroll
    for (int off = 32; off; off >>= 1) {
        pi += __shfl_xor(pi, off, 64);
        pj += __shfl_xor(pj, off, 64);
    }
    __shared__ float r[4];
    if ((f & 63) == 0) { r[(f >> 6) * 2 + 0] = pi; r[(f >> 6) * 2 + 1] = pj; }
    __syncthreads();
    if (f == 0) { s_i[i] = r[0] + r[2]; s_j[i] = r[1] + r[3]; }
}

// Kernel 2: one block (512 thr, 8 waves) per row i.
// float4/lane => one wave instruction covers 2 rows (lanes 0-31 row j, 32-63 row j+1).
// time_enc via CACHED loads (L3 serves ~half across replays); H via nt stores.
__global__ __launch_bounds__(512, 8) void gat_main(
    const float* __restrict__ time_enc, // N*N*F
    const float* __restrict__ E,        // N*N
    const float* __restrict__ Vp,       // N*F
    const float* __restrict__ s_i,      // N
    const float* __restrict__ s_j,      // N
    const float* __restrict__ a_t,      // F
    float* __restrict__ H)              // N*N*F
{
    const int i    = blockIdx.x;
    const int tid  = threadIdx.x;
    const int wave = tid >> 6;   // 0..7
    const int lane = tid & 63;
    const int half = lane >> 5;  // which row of the pair
    const int hl   = lane & 31;  // feature-chunk index within half

    __shared__ float sc[N];      // scores -> exp
    __shared__ float sjs[N];     // staged s_j
    __shared__ float Esh[N];     // staged E row
    __shared__ float red[16];

    const float* Erow = E + (size_t)i * N;
    for (int j = tid; j < N; j += 512) { sjs[j] = s_j[j]; Esh[j] = Erow[j]; }

    const f32x4 at4 = *reinterpret_cast<const f32x4*>(a_t + 4 * hl);
    const float si  = s_i[i];
    const float* te_row = time_enc + (size_t)i * N * F;
    __syncthreads();

    // Phase 1: scores + leaky_relu + per-wave max (x2 unroll = 4 rows/iter)
    float lmax = -INFINITY;
    for (int jb = wave * 4; jb < N; jb += 32) {
        const f32x4 t0 = *reinterpret_cast<const f32x4*>(te_row + (size_t)(jb + half) * F + 4 * hl);
        const f32x4 t1 = *reinterpret_cast<const f32x4*>(te_row + (size_t)(jb + 2 + half) * F + 4 * hl);
        float d0 = t0.x * at4.x + t0.y * at4.y + t0.z * at4.z + t0.w * at4.w;
        float d1 = t1.x * at4.x + t1.y * at4.y + t1.z * at4.z + t1.w * at4.w;
#pragma unroll
        for (int off = 16; off; off >>= 1) {
            d0 += __shfl_xor(d0, off, 64);
            d1 += __shfl_xor(d1, off, 64);
        }
        if (hl == 0) {   // lanes 0 and 32 hold full row sums
            float s0 = si + sjs[jb + half] + d0;
            float s1 = si + sjs[jb + 2 + half] + d1;
            s0 = (s0 > 0.f) ? s0 : NEG_SLOPE * s0;
            s1 = (s1 > 0.f) ? s1 : NEG_SLOPE * s1;
            sc[jb + half] = s0;
            sc[jb + 2 + half] = s1;
            lmax = fmaxf(lmax, fmaxf(s0, s1));
        }
    }
    lmax = fmaxf(lmax, __shfl_xor(lmax, 32, 64));
    if (lane == 0) red[wave] = lmax;
    __syncthreads();
    float m = red[0];
#pragma unroll
    for (int w = 1; w < 8; ++w) m = fmaxf(m, red[w]);

    // Phase 2: exp + sum
    float lsum = 0.f;
    for (int j = tid; j < N; j += 512) {
        float e = __expf(sc[j] - m);
        sc[j] = e;
        lsum += e;
    }
#pragma unroll
    for (int off = 32; off; off >>= 1) lsum += __shfl_xor(lsum, off, 64);
    if (lane == 0) red[8 + wave] = lsum;
    __syncthreads();
    float tot = red[8];
#pragma unroll
    for (int w = 1; w < 8; ++w) tot += red[8 + w];
    const float inv = 1.f / tot;

    // Phase 3: H[i,j,:] = (sc[j]*inv*E[i,j]) * Vp[j,:]   (x2 unroll)
    float* Hrow = H + (size_t)i * N * F;
    for (int jb = wave * 4; jb < N; jb += 32) {
        const f32x4 v0 = *reinterpret_cast<const f32x4*>(Vp + (size_t)(jb + half) * F + 4 * hl);
        const f32x4 v1 = *reinterpret_cast<const f32x4*>(Vp + (size_t)(jb + 2 + half) * F + 4 * hl);
        const float k0 = sc[jb + half] * inv * Esh[jb + half];
        const float k1 = sc[jb + 2 + half] * inv * Esh[jb + 2 + half];
        __builtin_nontemporal_store(v0 * k0,
            reinterpret_cast<f32x4*>(Hrow + (size_t)(jb + half) * F + 4 * hl));
        __builtin_nontemporal_store(v1 * k1,
            reinterpret_cast<f32x4*>(Hrow + (size_t)(jb + 2 + half) * F + 4 * hl));
    }
}

extern "C" void kernel_launch(void* const* d_in, const int* in_sizes, int n_in,
                              void* d_out, int out_size, void* d_ws, size_t ws_size,
                              hipStream_t stream) {
    const float* V  = (const float*)d_in[0];  // N*F
    const float* E  = (const float*)d_in[1];  // N*N
    const float* TE = (const float*)d_in[2];  // N*N*F
    const float* W  = (const float*)d_in[3];  // F*F
    const float* Wb = (const float*)d_in[4];  // F
    const float* a  = (const float*)d_in[5];  // 3F

    float* H = (float*)d_out;

    float* Vp  = (float*)d_ws;
    float* s_i = Vp + (size_t)N * F;
    float* s_j = s_i + N;

    gat_prep<<<N, 128, 0, stream>>>(V, W, Wb, a, Vp, s_i, s_j);
    gat_main<<<N, 512, 0, stream>>>(TE, E, Vp, s_i, s_j, a + 2 * F, H);
}

// Round 5
// 197.936 us; speedup vs baseline: 1.1014x; 1.1014x over previous
//
#include <hip/hip_runtime.h>
#include <hip/hip_bf16.h>
#include <math.h>

#define N 1024
#define F 128
#define NEG_SLOPE 0.01f

typedef float f32x4 __attribute__((ext_vector_type(4)));

// Kernel 1: Vp = V @ W^T + b ; s_i = Vp @ a_i ; s_j = Vp @ a_j
__global__ __launch_bounds__(128) void gat_prep(
    const float* __restrict__ V,     // N*F
    const float* __restrict__ W,     // F*F
    const float* __restrict__ b,     // F
    const float* __restrict__ a,     // 3F: [a_i | a_j | a_t]
    float* __restrict__ Vp,          // N*F
    float* __restrict__ s_i,         // N
    float* __restrict__ s_j)         // N
{
    const int i = blockIdx.x;
    const int f = threadIdx.x;        // 0..127
    __shared__ float vsh[F];
    vsh[f] = V[i * F + f];
    __syncthreads();

    const float* wrow = W + f * F;
    float acc = b[f];
#pragma unroll 4
    for (int k = 0; k < F; ++k) acc += vsh[k] * wrow[k];
    Vp[(size_t)i * F + f] = acc;

    float pi = acc * a[f];
    float pj = acc * a[F + f];
#pragma unroll
    for (int off = 32; off; off >>= 1) {
        pi += __shfl_xor(pi, off, 64);
        pj += __shfl_xor(pj, off, 64);
    }
    __shared__ float r[4];
    if ((f & 63) == 0) { r[(f >> 6) * 2 + 0] = pi; r[(f >> 6) * 2 + 1] = pj; }
    __syncthreads();
    if (f == 0) { s_i[i] = r[0] + r[2]; s_j[i] = r[1] + r[3]; }
}

// Kernel 2: one block (512 thr, 8 waves) per row i.
// float4/lane => one wave instruction covers 2 rows (lanes 0-31 row j, 32-63 row j+1).
// time_enc: NT loads (streamed once; keep L2 clean for Vp). H: plain stores.
__global__ __launch_bounds__(512, 8) void gat_main(
    const float* __restrict__ time_enc, // N*N*F
    const float* __restrict__ E,        // N*N
    const float* __restrict__ Vp,       // N*F
    const float* __restrict__ s_i,      // N
    const float* __restrict__ s_j,      // N
    const float* __restrict__ a_t,      // F
    float* __restrict__ H)              // N*N*F
{
    const int i    = blockIdx.x;
    const int tid  = threadIdx.x;
    const int wave = tid >> 6;   // 0..7
    const int lane = tid & 63;
    const int half = lane >> 5;  // which row of the pair
    const int hl   = lane & 31;  // feature-chunk index within half

    __shared__ float sc[N];      // scores -> exp
    __shared__ float sjs[N];     // staged s_j
    __shared__ float Esh[N];     // staged E row
    __shared__ float red[16];

    const float* Erow = E + (size_t)i * N;
    for (int j = tid; j < N; j += 512) { sjs[j] = s_j[j]; Esh[j] = Erow[j]; }

    const f32x4 at4 = *reinterpret_cast<const f32x4*>(a_t + 4 * hl);
    const float si  = s_i[i];
    const float* te_row = time_enc + (size_t)i * N * F;
    __syncthreads();

    // Phase 1: scores + leaky_relu + per-wave max (x2 unroll = 4 rows/iter)
    float lmax = -INFINITY;
    for (int jb = wave * 4; jb < N; jb += 32) {
        const f32x4 t0 = __builtin_nontemporal_load(
            reinterpret_cast<const f32x4*>(te_row + (size_t)(jb + half) * F + 4 * hl));
        const f32x4 t1 = __builtin_nontemporal_load(
            reinterpret_cast<const f32x4*>(te_row + (size_t)(jb + 2 + half) * F + 4 * hl));
        float d0 = t0.x * at4.x + t0.y * at4.y + t0.z * at4.z + t0.w * at4.w;
        float d1 = t1.x * at4.x + t1.y * at4.y + t1.z * at4.z + t1.w * at4.w;
#pragma unroll
        for (int off = 16; off; off >>= 1) {
            d0 += __shfl_xor(d0, off, 64);
            d1 += __shfl_xor(d1, off, 64);
        }
        if (hl == 0) {   // lanes 0 and 32 hold full row sums
            float s0 = si + sjs[jb + half] + d0;
            float s1 = si + sjs[jb + 2 + half] + d1;
            s0 = (s0 > 0.f) ? s0 : NEG_SLOPE * s0;
            s1 = (s1 > 0.f) ? s1 : NEG_SLOPE * s1;
            sc[jb + half] = s0;
            sc[jb + 2 + half] = s1;
            lmax = fmaxf(lmax, fmaxf(s0, s1));
        }
    }
    lmax = fmaxf(lmax, __shfl_xor(lmax, 32, 64));
    if (lane == 0) red[wave] = lmax;
    __syncthreads();
    float m = red[0];
#pragma unroll
    for (int w = 1; w < 8; ++w) m = fmaxf(m, red[w]);

    // Phase 2: exp + sum
    float lsum = 0.f;
    for (int j = tid; j < N; j += 512) {
        float e = __expf(sc[j] - m);
        sc[j] = e;
        lsum += e;
    }
#pragma unroll
    for (int off = 32; off; off >>= 1) lsum += __shfl_xor(lsum, off, 64);
    if (lane == 0) red[8 + wave] = lsum;
    __syncthreads();
    float tot = red[8];
#pragma unroll
    for (int w = 1; w < 8; ++w) tot += red[8 + w];
    const float inv = 1.f / tot;

    // Phase 3: H[i,j,:] = (sc[j]*inv*E[i,j]) * Vp[j,:]   (x2 unroll, plain stores)
    float* Hrow = H + (size_t)i * N * F;
    for (int jb = wave * 4; jb < N; jb += 32) {
        const f32x4 v0 = *reinterpret_cast<const f32x4*>(Vp + (size_t)(jb + half) * F + 4 * hl);
        const f32x4 v1 = *reinterpret_cast<const f32x4*>(Vp + (size_t)(jb + 2 + half) * F + 4 * hl);
        const float k0 = sc[jb + half] * inv * Esh[jb + half];
        const float k1 = sc[jb + 2 + half] * inv * Esh[jb + 2 + half];
        *reinterpret_cast<f32x4*>(Hrow + (size_t)(jb + half) * F + 4 * hl) = v0 * k0;
        *reinterpret_cast<f32x4*>(Hrow + (size_t)(jb + 2 + half) * F + 4 * hl) = v1 * k1;
    }
}

extern "C" void kernel_launch(void* const* d_in, const int* in_sizes, int n_in,
                              void* d_out, int out_size, void* d_ws, size_t ws_size,
                              hipStream_t stream) {
    const float* V  = (const float*)d_in[0];  // N*F
    const float* E  = (const float*)d_in[1];  // N*N
    const float* TE = (const float*)d_in[2];  // N*N*F
    const float* W  = (const float*)d_in[3];  // F*F
    const float* Wb = (const float*)d_in[4];  // F
    const float* a  = (const float*)d_in[5];  // 3F

    float* H = (float*)d_out;

    float* Vp  = (float*)d_ws;
    float* s_i = Vp + (size_t)N * F;
    float* s_j = s_i + N;

    gat_prep<<<N, 128, 0, stream>>>(V, W, Wb, a, Vp, s_i, s_j);
    gat_main<<<N, 512, 0, stream>>>(TE, E, Vp, s_i, s_j, a + 2 * F, H);
}